// Round 5
// baseline (132.645 us; speedup 1.0000x reference)
//
#include <hip/hip_runtime.h>

// YOLO v1 loss, fp32. preds/labels: [B, 7, 7, 30] fp32. Output: scalar fp32.
// One block = one 256-cell chunk. All 16 float4 loads (preds+labels) issued
// back-to-back into registers (single latency exposure), then two-phase
// transpose through ONE 30 KiB LDS buffer. Fused last-block finalize.

#define LAMBDA_COORD 5.0f
#define LAMBDA_NOOBJ 0.5f

#define CHUNK_CELLS 256
#define CHUNK_FLOATS (CHUNK_CELLS * 30)   // 7680 floats = 30720 B
#define CHUNK_F4 (CHUNK_FLOATS / 4)       // 1920 float4

__device__ __forceinline__ float iou_xywh(const float* b1, const float* b2) {
    float b1x1 = b1[0] - b1[2] * 0.5f;
    float b1y1 = b1[1] - b1[3] * 0.5f;
    float b1x2 = b1[0] + b1[2] * 0.5f;
    float b1y2 = b1[1] + b1[3] * 0.5f;
    float b2x1 = b2[0] - b2[2] * 0.5f;
    float b2y1 = b2[1] - b2[3] * 0.5f;
    float b2x2 = b2[0] + b2[2] * 0.5f;
    float b2y2 = b2[1] + b2[3] * 0.5f;
    float iw = fmaxf(fminf(b1x2, b2x2) - fmaxf(b1x1, b2x1), 0.0f);
    float ih = fmaxf(fminf(b1y2, b2y2) - fmaxf(b1y1, b2y1), 0.0f);
    float inter = iw * ih;
    float area1 = (b1x2 - b1x1) * (b1y2 - b1y1);
    float area2 = (b2x2 - b2x1) * (b2y2 - b2y1);
    return inter / (area1 + area2 - inter + 1e-10f);
}

__device__ __forceinline__ float cell_loss(const float* __restrict__ p,
                                           const float* __restrict__ l) {
    bool obj  = (l[4] == 1.0f);
    float iou1 = iou_xywh(p + 0, l + 0);
    float iou2 = iou_xywh(p + 5, l + 0);
    bool box1 = (iou1 > iou2);

    float dx1 = l[0] - p[0], dy1 = l[1] - p[1];
    float xy1 = dx1 * dx1 + dy1 * dy1;
    float dx2 = l[5] - p[5], dy2 = l[6] - p[6];
    float xy2 = dx2 * dx2 + dy2 * dy2;

    float dw1 = sqrtf(l[2]) - sqrtf(p[2]);
    float dh1 = sqrtf(l[3]) - sqrtf(p[3]);
    float wh1 = dw1 * dw1 + dh1 * dh1;
    float dw2 = sqrtf(l[7]) - sqrtf(p[7]);
    float dh2 = sqrtf(l[8]) - sqrtf(p[8]);
    float wh2 = dw2 * dw2 + dh2 * dh2;

    float dc1 = l[4] - p[4];
    float conf1 = dc1 * dc1;
    float dc2 = l[9] - p[9];
    float conf2 = dc2 * dc2;

    float cls = 0.0f;
    #pragma unroll
    for (int k = 10; k < 30; ++k) {
        float d = l[k] - p[k];
        cls = fmaf(d, d, cls);
    }

    if (obj) {
        float xy  = box1 ? xy1 : xy2;
        float wh  = box1 ? wh1 : wh2;
        float cf  = box1 ? conf1 : conf2;
        float no  = box1 ? p[9] * p[9] : p[4] * p[4];
        return LAMBDA_COORD * (xy + wh) + cf + LAMBDA_NOOBJ * no + cls;
    } else {
        return LAMBDA_NOOBJ * (p[4] * p[4] + p[9] * p[9]);
    }
}

__device__ __forceinline__ float block_reduce_sum(float v, float* smem) {
    #pragma unroll
    for (int off = 32; off > 0; off >>= 1)
        v += __shfl_down(v, off, 64);
    int lane = threadIdx.x & 63;
    int wid  = threadIdx.x >> 6;
    if (lane == 0) smem[wid] = v;
    __syncthreads();
    float total = 0.0f;
    if (threadIdx.x == 0) {
        int nw = blockDim.x >> 6;
        for (int i = 0; i < nw; ++i) total += smem[i];
    }
    return total;  // valid only on thread 0
}

__global__ void __launch_bounds__(256, 2) yolo_loss(
        const float* __restrict__ preds,
        const float* __restrict__ labels,
        float* __restrict__ out,
        float* __restrict__ partial,
        unsigned int* __restrict__ counter,
        int ncells, float inv_batch) {
    __shared__ float buf[CHUNK_FLOATS];        // 30720 B, reused P then L
    __shared__ float smem[4];
    __shared__ float smem2[4];
    __shared__ int is_last;

    int tid = threadIdx.x;
    int nchunks = (ncells + CHUNK_CELLS - 1) / CHUNK_CELLS;
    float acc = 0.0f;

    for (int chunk = blockIdx.x; chunk < nchunks; chunk += gridDim.x) {
        size_t fbase = (size_t)chunk * CHUNK_FLOATS;
        int cells_here = ncells - chunk * CHUNK_CELLS;
        if (cells_here > CHUNK_CELLS) cells_here = CHUNK_CELLS;
        int nfl = cells_here * 30;
        int nf4 = nfl >> 2;                    // full chunks: 1920
        bool valid = (tid < cells_here);

        const float4* gp = reinterpret_cast<const float4*>(preds + fbase);
        const float4* gl = reinterpret_cast<const float4*>(labels + fbase);

        // ---- issue ALL loads up front: 16 independent float4 in flight ----
        float4 P[8], L[8];
        #pragma unroll
        for (int i = 0; i < 8; ++i) {
            int fi = tid + 256 * i;
            P[i] = (fi < nf4) ? gp[fi] : make_float4(0.f, 0.f, 0.f, 0.f);
        }
        #pragma unroll
        for (int i = 0; i < 8; ++i) {
            int fi = tid + 256 * i;
            L[i] = (fi < nf4) ? gl[fi] : make_float4(0.f, 0.f, 0.f, 0.f);
        }

        // ---- phase 1: preds through LDS ----
        #pragma unroll
        for (int i = 0; i < 8; ++i) {
            int fi = tid + 256 * i;
            if (fi < nf4) *reinterpret_cast<float4*>(&buf[fi * 4]) = P[i];
        }
        for (int r = nf4 * 4 + tid; r < nfl; r += 256)   // ragged tail floats
            buf[r] = preds[fbase + r];
        __syncthreads();

        float p[30];
        if (valid) {
            const float2* b2 = reinterpret_cast<const float2*>(buf);
            #pragma unroll
            for (int i = 0; i < 15; ++i) {
                float2 t = b2[tid * 15 + i];
                p[2 * i]     = t.x;
                p[2 * i + 1] = t.y;
            }
        }
        __syncthreads();

        // ---- phase 2: labels through same LDS (data already in regs) ----
        #pragma unroll
        for (int i = 0; i < 8; ++i) {
            int fi = tid + 256 * i;
            if (fi < nf4) *reinterpret_cast<float4*>(&buf[fi * 4]) = L[i];
        }
        for (int r = nf4 * 4 + tid; r < nfl; r += 256)
            buf[r] = labels[fbase + r];
        __syncthreads();

        float l[30];
        if (valid) {
            const float2* b2 = reinterpret_cast<const float2*>(buf);
            #pragma unroll
            for (int i = 0; i < 15; ++i) {
                float2 t = b2[tid * 15 + i];
                l[2 * i]     = t.x;
                l[2 * i + 1] = t.y;
            }
        }
        __syncthreads();                       // buf reads done before next chunk

        if (valid) acc += cell_loss(p, l);
    }

    float bsum = block_reduce_sum(acc, smem);
    if (tid == 0) {
        partial[blockIdx.x] = bsum;
        __threadfence();
        unsigned int prev = atomicAdd(counter, 1u);
        is_last = (prev == gridDim.x - 1) ? 1 : 0;
    }
    __syncthreads();

    if (is_last) {
        __threadfence();
        float a = 0.0f;
        for (int i = tid; i < (int)gridDim.x; i += blockDim.x)
            a += partial[i];                   // fixed order -> deterministic
        float total = block_reduce_sum(a, smem2);
        if (tid == 0) out[0] = total * inv_batch;
    }
}

extern "C" void kernel_launch(void* const* d_in, const int* in_sizes, int n_in,
                              void* d_out, int out_size, void* d_ws, size_t ws_size,
                              hipStream_t stream) {
    const float* preds  = (const float*)d_in[0];
    const float* labels = (const float*)d_in[1];
    float* out = (float*)d_out;

    int ncells = in_sizes[0] / 30;            // B * 7 * 7
    int batch  = ncells / 49;
    float inv_batch = 1.0f / (float)batch;

    int nchunks = (ncells + CHUNK_CELLS - 1) / CHUNK_CELLS;  // 3136 at B=16384
    int grid = nchunks;
    int maxblocks = (int)((ws_size - sizeof(unsigned int)) / sizeof(float));
    if (grid > maxblocks) grid = maxblocks;   // grid-stride covers the rest
    if (grid > 8192) grid = 8192;
    if (grid < 1) grid = 1;

    float* partial = (float*)d_ws;
    unsigned int* counter = (unsigned int*)((char*)d_ws + (size_t)grid * sizeof(float));

    hipMemsetAsync(counter, 0, sizeof(unsigned int), stream);
    yolo_loss<<<grid, 256, 0, stream>>>(preds, labels, out, partial, counter,
                                        ncells, inv_batch);
}

// Round 6
// 109.478 us; speedup vs baseline: 1.2116x; 1.2116x over previous
//
#include <hip/hip_runtime.h>

// YOLO v1 loss, fp32. preds/labels: [B, 7, 7, 30] fp32. Output: scalar fp32.
// Per-WAVE private LDS staging (no __syncthreads in hot path): each wave
// stages 64 cells of preds into its private 7.68KB buffer with coalesced
// float4 loads, extracts to registers, reuses the SAME buffer for labels.
// Correctness of wave-synchronous LDS use proven by round-2 kernel; explicit
// lgkmcnt(0) fence guards the write-after-read buffer reuse.
// Fused deterministic last-block finalize.

#define LAMBDA_COORD 5.0f
#define LAMBDA_NOOBJ 0.5f

#define CPW 64                      // cells per wave
#define WAVE_FLOATS (CPW * 30)      // 1920 floats = 7680 B per wave buffer

__device__ __forceinline__ float iou_xywh(const float* b1, const float* b2) {
    float b1x1 = b1[0] - b1[2] * 0.5f;
    float b1y1 = b1[1] - b1[3] * 0.5f;
    float b1x2 = b1[0] + b1[2] * 0.5f;
    float b1y2 = b1[1] + b1[3] * 0.5f;
    float b2x1 = b2[0] - b2[2] * 0.5f;
    float b2y1 = b2[1] - b2[3] * 0.5f;
    float b2x2 = b2[0] + b2[2] * 0.5f;
    float b2y2 = b2[1] + b2[3] * 0.5f;
    float iw = fmaxf(fminf(b1x2, b2x2) - fmaxf(b1x1, b2x1), 0.0f);
    float ih = fmaxf(fminf(b1y2, b2y2) - fmaxf(b1y1, b2y1), 0.0f);
    float inter = iw * ih;
    float area1 = (b1x2 - b1x1) * (b1y2 - b1y1);
    float area2 = (b2x2 - b2x1) * (b2y2 - b2y1);
    return inter / (area1 + area2 - inter + 1e-10f);
}

__device__ __forceinline__ float cell_loss(const float* __restrict__ p,
                                           const float* __restrict__ l) {
    bool obj  = (l[4] == 1.0f);
    float iou1 = iou_xywh(p + 0, l + 0);
    float iou2 = iou_xywh(p + 5, l + 0);
    bool box1 = (iou1 > iou2);

    float dx1 = l[0] - p[0], dy1 = l[1] - p[1];
    float xy1 = dx1 * dx1 + dy1 * dy1;
    float dx2 = l[5] - p[5], dy2 = l[6] - p[6];
    float xy2 = dx2 * dx2 + dy2 * dy2;

    float dw1 = sqrtf(l[2]) - sqrtf(p[2]);
    float dh1 = sqrtf(l[3]) - sqrtf(p[3]);
    float wh1 = dw1 * dw1 + dh1 * dh1;
    float dw2 = sqrtf(l[7]) - sqrtf(p[7]);
    float dh2 = sqrtf(l[8]) - sqrtf(p[8]);
    float wh2 = dw2 * dw2 + dh2 * dh2;

    float dc1 = l[4] - p[4];
    float conf1 = dc1 * dc1;
    float dc2 = l[9] - p[9];
    float conf2 = dc2 * dc2;

    float cls = 0.0f;
    #pragma unroll
    for (int k = 10; k < 30; ++k) {
        float d = l[k] - p[k];
        cls = fmaf(d, d, cls);
    }

    if (obj) {
        float xy  = box1 ? xy1 : xy2;
        float wh  = box1 ? wh1 : wh2;
        float cf  = box1 ? conf1 : conf2;
        float no  = box1 ? p[9] * p[9] : p[4] * p[4];
        return LAMBDA_COORD * (xy + wh) + cf + LAMBDA_NOOBJ * no + cls;
    } else {
        return LAMBDA_NOOBJ * (p[4] * p[4] + p[9] * p[9]);
    }
}

__device__ __forceinline__ float block_reduce_sum(float v, float* smem) {
    #pragma unroll
    for (int off = 32; off > 0; off >>= 1)
        v += __shfl_down(v, off, 64);
    int lane = threadIdx.x & 63;
    int wid  = threadIdx.x >> 6;
    if (lane == 0) smem[wid] = v;
    __syncthreads();
    float total = 0.0f;
    if (threadIdx.x == 0) {
        int nw = blockDim.x >> 6;
        for (int i = 0; i < nw; ++i) total += smem[i];
    }
    return total;  // valid only on thread 0
}

// Coalesced per-wave staging: wave's 64 lanes load nflv floats starting at g
// (16B-aligned) into the wave-private LDS region sb.
__device__ __forceinline__ void stage_wave(const float* __restrict__ g,
                                           float* __restrict__ sb,
                                           int lane, int nflv) {
    const float4* g4 = reinterpret_cast<const float4*>(g);
    int nf4 = nflv >> 2;                       // 480 for a full wave
    #pragma unroll
    for (int i = 0; i < 8; ++i) {              // 8*64 = 512 >= 480
        int fi = lane + (i << 6);
        if (fi < nf4)
            *reinterpret_cast<float4*>(sb + fi * 4) = g4[fi];
    }
    for (int r = (nf4 << 2) + lane; r < nflv; r += 64)   // ragged tail
        sb[r] = g[r];
}

__global__ void __launch_bounds__(256) yolo_loss(
        const float* __restrict__ preds,
        const float* __restrict__ labels,
        float* __restrict__ out,
        float* __restrict__ partial,
        unsigned int* __restrict__ counter,
        int ncells, float inv_batch) {
    __shared__ alignas(16) float buf[4][WAVE_FLOATS];   // 30720 B
    __shared__ float smem[4];
    __shared__ float smem2[4];
    __shared__ int is_last;

    int tid  = threadIdx.x;
    int lane = tid & 63;
    int wid  = tid >> 6;
    float* sb = buf[wid];

    int nchunks = (ncells + 255) / 256;        // 256 cells per block-chunk
    float acc = 0.0f;

    for (int chunk = blockIdx.x; chunk < nchunks; chunk += gridDim.x) {
        int cell0 = chunk * 256 + wid * CPW;   // first cell of this wave
        int wvalid = ncells - cell0;
        if (wvalid <= 0) continue;             // no barriers in loop -> safe
        if (wvalid > CPW) wvalid = CPW;
        int nflv = wvalid * 30;

        const float* gp = preds  + (size_t)cell0 * 30;   // cell0*120B: 16B-aligned
        const float* gl = labels + (size_t)cell0 * 30;

        // WAR fence: prior iteration's extract ds_reads drained before overwrite
        asm volatile("s_waitcnt lgkmcnt(0)" ::: "memory");

        // ---- phase 1: preds through wave-private LDS ----
        stage_wave(gp, sb, lane, nflv);
        float p[30];
        if (lane < wvalid) {
            const float2* b2 = reinterpret_cast<const float2*>(sb);
            #pragma unroll
            for (int i = 0; i < 15; ++i) {
                float2 t = b2[lane * 15 + i];
                p[2 * i]     = t.x;
                p[2 * i + 1] = t.y;
            }
        }

        // WAR fence before reusing the buffer for labels
        asm volatile("s_waitcnt lgkmcnt(0)" ::: "memory");

        // ---- phase 2: labels through the same buffer ----
        stage_wave(gl, sb, lane, nflv);
        if (lane < wvalid) {
            const float2* b2 = reinterpret_cast<const float2*>(sb);
            float l[30];
            #pragma unroll
            for (int i = 0; i < 15; ++i) {
                float2 t = b2[lane * 15 + i];
                l[2 * i]     = t.x;
                l[2 * i + 1] = t.y;
            }
            acc += cell_loss(p, l);
        }
    }

    float bsum = block_reduce_sum(acc, smem);
    if (tid == 0) {
        partial[blockIdx.x] = bsum;
        __threadfence();
        unsigned int prev = atomicAdd(counter, 1u);
        is_last = (prev == gridDim.x - 1) ? 1 : 0;
    }
    __syncthreads();

    if (is_last) {
        __threadfence();
        float a = 0.0f;
        for (int i = tid; i < (int)gridDim.x; i += blockDim.x)
            a += partial[i];                   // fixed order -> deterministic
        float total = block_reduce_sum(a, smem2);
        if (tid == 0) out[0] = total * inv_batch;
    }
}

extern "C" void kernel_launch(void* const* d_in, const int* in_sizes, int n_in,
                              void* d_out, int out_size, void* d_ws, size_t ws_size,
                              hipStream_t stream) {
    const float* preds  = (const float*)d_in[0];
    const float* labels = (const float*)d_in[1];
    float* out = (float*)d_out;

    int ncells = in_sizes[0] / 30;             // B * 7 * 7
    int batch  = ncells / 49;
    float inv_batch = 1.0f / (float)batch;

    int nchunks = (ncells + 255) / 256;        // 3136 at B=16384
    int grid = nchunks;
    int maxblocks = (int)((ws_size - sizeof(unsigned int)) / sizeof(float));
    if (grid > maxblocks) grid = maxblocks;    // grid-stride covers the rest
    if (grid > 8192) grid = 8192;
    if (grid < 1) grid = 1;

    float* partial = (float*)d_ws;
    unsigned int* counter = (unsigned int*)((char*)d_ws + (size_t)grid * sizeof(float));

    hipMemsetAsync(counter, 0, sizeof(unsigned int), stream);
    yolo_loss<<<grid, 256, 0, stream>>>(preds, labels, out, partial, counter,
                                        ncells, inv_batch);
}